// Round 4
// baseline (449.631 us; speedup 1.0000x reference)
//
#include <hip/hip_runtime.h>
#include <stdint.h>

#define NB 8192
#define NP 1024
#define ND 2048
#define KSEL 5

typedef unsigned short u16;
typedef unsigned int u32;
typedef unsigned long long u64;
typedef __attribute__((ext_vector_type(8))) short bf16x8;
typedef __attribute__((ext_vector_type(8))) u16 u16x8;
typedef __attribute__((ext_vector_type(4))) u16 u16x4;
typedef __attribute__((ext_vector_type(4))) float f32x4;

// Small persistent scratch only (~260 KB). Large scratch either lives in d_ws
// (ONLY if ws_size is verified big enough) or is avoided entirely.
// OUTPUT IS FLOAT32 (reference returns f32; rounds 0-3 failed from writing bf16:
// error 56833.94 == f32 0x475E0000 == two packed bf16 scalars read as one f32).
__device__ float g_knf[NP];
__device__ int   g_cidx[NB * 8];
__device__ float g_scal[2];   // [0]=sel_sum [1]=entropy

__device__ __forceinline__ u16 f2bf_rne(float f) {
    u32 u = __float_as_uint(f);
    u = (u + 0x7fffu + ((u >> 16) & 1u)) >> 16;
    return (u16)u;
}

__global__ void init_scal() {
    if (threadIdx.x == 0 && blockIdx.x == 0) { g_scal[0] = 0.f; g_scal[1] = 0.f; }
}

// ---------------- prep (fast path): f32 -> bf16 planes + key norms ----------------

__global__ __launch_bounds__(256) void prep_q(const float* __restrict__ q,
                                              u16* __restrict__ qb) {
    const int r = blockIdx.x, t = threadIdx.x;
    const float* row = q + (size_t)r * ND;
    float4 a = *(const float4*)(row + t * 8);
    float4 b = *(const float4*)(row + t * 8 + 4);
    u16x8 v;
    v[0] = f2bf_rne(a.x); v[1] = f2bf_rne(a.y); v[2] = f2bf_rne(a.z); v[3] = f2bf_rne(a.w);
    v[4] = f2bf_rne(b.x); v[5] = f2bf_rne(b.y); v[6] = f2bf_rne(b.z); v[7] = f2bf_rne(b.w);
    *(u16x8*)(qb + (size_t)r * ND + t * 8) = v;
}

__global__ __launch_bounds__(256) void prep_k(const float* __restrict__ k,
                                              u16* __restrict__ kb) {
    const int r = blockIdx.x, t = threadIdx.x;
    const float* row = k + (size_t)r * ND;
    float4 a = *(const float4*)(row + t * 8);
    float4 b = *(const float4*)(row + t * 8 + 4);
    if (kb) {
        u16x8 v;
        v[0] = f2bf_rne(a.x); v[1] = f2bf_rne(a.y); v[2] = f2bf_rne(a.z); v[3] = f2bf_rne(a.w);
        v[4] = f2bf_rne(b.x); v[5] = f2bf_rne(b.y); v[6] = f2bf_rne(b.z); v[7] = f2bf_rne(b.w);
        *(u16x8*)(kb + (size_t)r * ND + t * 8) = v;
    }
    float ss = a.x*a.x + a.y*a.y + a.z*a.z + a.w*a.w
             + b.x*b.x + b.y*b.y + b.z*b.z + b.w*b.w;
    for (int off = 32; off; off >>= 1) ss += __shfl_xor(ss, off);
    __shared__ float red[4];
    if ((t & 63) == 0) red[t >> 6] = ss;
    __syncthreads();
    if (t == 0) g_knf[r] = sqrtf(red[0] + red[1] + red[2] + red[3]);
}

// ---------------- GEMM fast: bf16 planes + global_load_lds ----------------
// C[b,p] = raw dot(q_b, key_p) in f32, written into d_out's payload region.

__global__ __launch_bounds__(256) void gemm_fast(const u16* __restrict__ A,
                                                 const u16* __restrict__ B,
                                                 float* __restrict__ C) {
    __shared__ u16 As[128 * 64];
    __shared__ u16 Bs[128 * 64];
    const int t = threadIdx.x, w = t >> 6, l = t & 63;
    const int bid = blockIdx.x;
    const int m0 = (bid >> 3) << 7, n0 = (bid & 7) << 7;
    const int wr = w >> 1, wc = w & 1;

    f32x4 acc[4][4];
#pragma unroll
    for (int m = 0; m < 4; m++)
#pragma unroll
        for (int n = 0; n < 4; n++) acc[m][n] = (f32x4){0.f, 0.f, 0.f, 0.f};

    const int rowi = l >> 3, col8 = l & 7;
    const u16* Abase = A + (size_t)(m0 + w * 8 + rowi) * ND + col8 * 8;
    const u16* Bbase = B + (size_t)(n0 + w * 8 + rowi) * ND + col8 * 8;

    for (int k0 = 0; k0 < ND; k0 += 64) {
#pragma unroll
        for (int i = 0; i < 4; i++) {
            __builtin_amdgcn_global_load_lds(
                (const __attribute__((address_space(1))) void*)(Abase + (size_t)(i * 32) * ND + k0),
                (__attribute__((address_space(3))) void*)(&As[(i * 4 + w) * 512]),
                16, 0, 0);
            __builtin_amdgcn_global_load_lds(
                (const __attribute__((address_space(1))) void*)(Bbase + (size_t)(i * 32) * ND + k0),
                (__attribute__((address_space(3))) void*)(&Bs[(i * 4 + w) * 512]),
                16, 0, 0);
        }
        __syncthreads();
#pragma unroll
        for (int kk = 0; kk < 64; kk += 32) {
            bf16x8 af[4], bfr[4];
#pragma unroll
            for (int m = 0; m < 4; m++)
                af[m] = *(const bf16x8*)&As[(wr * 64 + m * 16 + (l & 15)) * 64 + kk + (l >> 4) * 8];
#pragma unroll
            for (int n = 0; n < 4; n++)
                bfr[n] = *(const bf16x8*)&Bs[(wc * 64 + n * 16 + (l & 15)) * 64 + kk + (l >> 4) * 8];
#pragma unroll
            for (int m = 0; m < 4; m++)
#pragma unroll
                for (int n = 0; n < 4; n++)
                    acc[m][n] = __builtin_amdgcn_mfma_f32_16x16x32_bf16(af[m], bfr[n], acc[m][n], 0, 0, 0);
        }
        __syncthreads();
    }

    const int lc = l & 15, lr4 = (l >> 4) * 4;
#pragma unroll
    for (int m = 0; m < 4; m++) {
        int rbase = m0 + wr * 64 + m * 16 + lr4;
#pragma unroll
        for (int n = 0; n < 4; n++) {
            int col = n0 + wc * 64 + n * 16 + lc;
#pragma unroll
            for (int r = 0; r < 4; r++)
                C[(size_t)(rbase + r) * NP + col] = acc[m][n][r];
        }
    }
}

// ---------------- GEMM slow: f32 inputs, convert to bf16 during LDS staging ----------------

__global__ __launch_bounds__(256) void gemm_slow(const float* __restrict__ A,
                                                 const float* __restrict__ B,
                                                 float* __restrict__ C) {
    __shared__ u16 As[128 * 64];
    __shared__ u16 Bs[128 * 64];
    const int t = threadIdx.x, w = t >> 6, l = t & 63;
    const int bid = blockIdx.x;
    const int m0 = (bid >> 3) << 7, n0 = (bid & 7) << 7;
    const int wr = w >> 1, wc = w & 1;

    f32x4 acc[4][4];
#pragma unroll
    for (int m = 0; m < 4; m++)
#pragma unroll
        for (int n = 0; n < 4; n++) acc[m][n] = (f32x4){0.f, 0.f, 0.f, 0.f};

    const int arow = t >> 4;   // 0..15
    const int acol4 = t & 15;  // float4 index in 64-wide K tile

    for (int k0 = 0; k0 < ND; k0 += 64) {
#pragma unroll
        for (int s = 0; s < 8; s++) {
            int row = s * 16 + arow;
            float4 va = *(const float4*)(A + (size_t)(m0 + row) * ND + k0 + acol4 * 4);
            u16x4 ba;
            ba[0] = f2bf_rne(va.x); ba[1] = f2bf_rne(va.y);
            ba[2] = f2bf_rne(va.z); ba[3] = f2bf_rne(va.w);
            *(u16x4*)&As[row * 64 + acol4 * 4] = ba;
            float4 vb = *(const float4*)(B + (size_t)(n0 + row) * ND + k0 + acol4 * 4);
            u16x4 bb;
            bb[0] = f2bf_rne(vb.x); bb[1] = f2bf_rne(vb.y);
            bb[2] = f2bf_rne(vb.z); bb[3] = f2bf_rne(vb.w);
            *(u16x4*)&Bs[row * 64 + acol4 * 4] = bb;
        }
        __syncthreads();
#pragma unroll
        for (int kk = 0; kk < 64; kk += 32) {
            bf16x8 af[4], bfr[4];
#pragma unroll
            for (int m = 0; m < 4; m++)
                af[m] = *(const bf16x8*)&As[(wr * 64 + m * 16 + (l & 15)) * 64 + kk + (l >> 4) * 8];
#pragma unroll
            for (int n = 0; n < 4; n++)
                bfr[n] = *(const bf16x8*)&Bs[(wc * 64 + n * 16 + (l & 15)) * 64 + kk + (l >> 4) * 8];
#pragma unroll
            for (int m = 0; m < 4; m++)
#pragma unroll
                for (int n = 0; n < 4; n++)
                    acc[m][n] = __builtin_amdgcn_mfma_f32_16x16x32_bf16(af[m], bfr[n], acc[m][n], 0, 0, 0);
        }
        __syncthreads();
    }

    const int lc = l & 15, lr4 = (l >> 4) * 4;
#pragma unroll
    for (int m = 0; m < 4; m++) {
        int rbase = m0 + wr * 64 + m * 16 + lr4;
#pragma unroll
        for (int n = 0; n < 4; n++) {
            int col = n0 + wc * 64 + n * 16 + lc;
#pragma unroll
            for (int r = 0; r < 4; r++)
                C[(size_t)(rbase + r) * NP + col] = acc[m][n][r];
        }
    }
}

// ---------------- per-row: qn + entropy + top-5 + scalar accumulation ----------------

__global__ __launch_bounds__(64) void rowstats(const float* __restrict__ C,
                                               const float* __restrict__ ppg) {
    const int r = blockIdx.x, l = threadIdx.x;

    // q norm from the f32 ppg row
    const float* prow = ppg + (size_t)r * ND;
    float ss = 0.f;
#pragma unroll
    for (int s2 = 0; s2 < 8; s2++) {
        float4 v = *(const float4*)(prow + (s2 * 64 + l) * 4);
        ss += v.x*v.x + v.y*v.y + v.z*v.z + v.w*v.w;
    }
    for (int off = 32; off; off >>= 1) ss += __shfl_xor(ss, off);
    float qn = sqrtf(ss);

    const float* crow = C + (size_t)r * NP;
    float s[16];
#pragma unroll
    for (int j = 0; j < 16; j++) {
        float dot = crow[j * 64 + l];
        float kn = g_knf[j * 64 + l];
        s[j] = 1.0f - dot / fmaxf(qn * kn, 1e-8f);
    }

    // entropy of softmax(s): ln(S0) - S1/S0 with d = s - max
    float mx = s[0];
#pragma unroll
    for (int j = 1; j < 16; j++) mx = fmaxf(mx, s[j]);
    for (int off = 32; off; off >>= 1) mx = fmaxf(mx, __shfl_xor(mx, off));
    float S0 = 0.f, S1 = 0.f;
#pragma unroll
    for (int j = 0; j < 16; j++) {
        float d = s[j] - mx;
        float e = __expf(d);
        S0 += e;
        S1 += d * e;
    }
    for (int off = 32; off; off >>= 1) {
        S0 += __shfl_xor(S0, off);
        S1 += __shfl_xor(S1, off);
    }

    // top-5 smallest s, tie-break = smallest index (top_k first-occurrence)
    unsigned used = 0;
    float ssum = 0.f;
    int ci[KSEL];
    for (int i = 0; i < KSEL; i++) {
        float bv = 3.0e38f;
        int bp = 0;
#pragma unroll
        for (int j = 0; j < 16; j++) {
            if (!((used >> j) & 1) && s[j] < bv) { bv = s[j]; bp = j * 64 + l; }
        }
        u64 u = ((u64)__float_as_uint(bv) << 32) | (u32)bp;
        for (int off = 32; off; off >>= 1) {
            u64 o = __shfl_xor(u, off);
            if (o < u) u = o;
        }
        int p = (int)(u & 0xffffffffu);
        ci[i] = p;
        ssum += __uint_as_float((u32)(u >> 32));
        if ((p & 63) == l) used |= 1u << (p >> 6);
    }
    if (l == 0) {
        atomicAdd(&g_scal[1], logf(S0) - S1 / S0);
        atomicAdd(&g_scal[0], ssum);
#pragma unroll
        for (int i = 0; i < KSEL; i++) g_cidx[r * 8 + i] = ci[i];
    }
}

// ---------------- gather + f32 output ----------------

__global__ __launch_bounds__(256) void gather_out(const float* __restrict__ ppg,
                                                  const float* __restrict__ prompt,
                                                  float* __restrict__ outp) {
    const int r = blockIdx.x, t = threadIdx.x;
    __shared__ int sel[KSEL];
    if (t < KSEL) sel[t] = g_cidx[r * 8 + t];
    __syncthreads();

    const float* prow = ppg + (size_t)r * ND + t * 8;
    float4 a = *(const float4*)prow;
    float4 b = *(const float4*)(prow + 4);
    float4 ax = {0, 0, 0, 0}, bx = {0, 0, 0, 0};
#pragma unroll
    for (int i = 0; i < KSEL; i++) {
        const float* pr = prompt + (size_t)sel[i] * ND + t * 8;
        float4 x = *(const float4*)pr;
        float4 y = *(const float4*)(pr + 4);
        ax.x += x.x; ax.y += x.y; ax.z += x.z; ax.w += x.w;
        bx.x += y.x; bx.y += y.y; bx.z += y.z; bx.w += y.w;
    }
    float4 oa = {a.x + 0.5f * ax.x, a.y + 0.5f * ax.y, a.z + 0.5f * ax.z, a.w + 0.5f * ax.w};
    float4 ob = {b.x + 0.5f * bx.x, b.y + 0.5f * bx.y, b.z + 0.5f * bx.z, b.w + 0.5f * bx.w};
    float* orow = outp + (size_t)r * ND + t * 8;
    *(float4*)orow = oa;
    *(float4*)(orow + 4) = ob;
}

__global__ void finalize(float* __restrict__ outp) {
    if (threadIdx.x == 0 && blockIdx.x == 0) {
        outp[(size_t)NB * ND] = g_scal[0];
        outp[(size_t)NB * ND + 1] = g_scal[1];
    }
}

extern "C" void kernel_launch(void* const* d_in, const int* in_sizes, int n_in,
                              void* d_out, int out_size, void* d_ws, size_t ws_size,
                              hipStream_t stream) {
    const float* ppg    = (const float*)d_in[0];
    const float* keys   = (const float*)d_in[1];
    const float* prompt = (const float*)d_in[2];
    float* outp = (float*)d_out;

    // The 32MB f32 dot matrix C lives in d_out's payload region [0 : NB*NP);
    // gemm writes it, rowstats consumes it, gather_out overwrites it (stream-ordered).
    float* C = (float*)d_out;

    // Fast path only if d_ws is verifiably large enough for bf16 planes.
    const size_t QB_BYTES = (size_t)NB * ND * 2;  // 33,554,432
    const size_t KB_BYTES = (size_t)NP * ND * 2;  //  4,194,304
    bool fast = (d_ws != nullptr) && (ws_size >= QB_BYTES + KB_BYTES);
    u16* qb = fast ? (u16*)d_ws : nullptr;
    u16* kb = fast ? (u16*)((char*)d_ws + QB_BYTES) : nullptr;

    init_scal<<<1, 64, 0, stream>>>();
    prep_k<<<NP, 256, 0, stream>>>(keys, kb);   // always computes g_knf
    if (fast) {
        prep_q<<<NB, 256, 0, stream>>>(ppg, qb);
        gemm_fast<<<(NB / 128) * (NP / 128), 256, 0, stream>>>(qb, kb, C);
    } else {
        gemm_slow<<<(NB / 128) * (NP / 128), 256, 0, stream>>>(ppg, keys, C);
    }
    rowstats<<<NB, 64, 0, stream>>>(C, ppg);
    gather_out<<<NB, 256, 0, stream>>>(ppg, prompt, outp);
    finalize<<<1, 64, 0, stream>>>(outp);
}

// Round 5
// 245.932 us; speedup vs baseline: 1.8283x; 1.8283x over previous
//
#include <hip/hip_runtime.h>
#include <stdint.h>

#define NB 8192
#define NP 1024
#define ND 2048
#define KSEL 5

typedef unsigned short u16;
typedef unsigned int u32;
typedef unsigned long long u64;
typedef __attribute__((ext_vector_type(8))) short bf16x8;
typedef __attribute__((ext_vector_type(8))) u16 u16x8;
typedef __attribute__((ext_vector_type(4))) u16 u16x4;
typedef __attribute__((ext_vector_type(4))) float f32x4;

// Output is FLOAT32 (reference dtype). d_ws only used when ws_size verified.
// Round-4 profile: rowstats was 223us of 449us -- 16384 same-address atomicAdds
// serialized. Replaced with per-row partials + one small reduce kernel.
__device__ float g_knf[NP];
__device__ float g_qn[NB];
__device__ float g_psel[NB];
__device__ float g_pent[NB];
__device__ int   g_cidx[NB * 8];

__device__ __forceinline__ u16 f2bf_rne(float f) {
    u32 u = __float_as_uint(f);
    u = (u + 0x7fffu + ((u >> 16) & 1u)) >> 16;
    return (u16)u;
}

// ---------------- prep: f32 -> bf16 planes + norms ----------------
// prep_q ALWAYS runs (computes g_qn); qb write only on fast path.

__global__ __launch_bounds__(256) void prep_q(const float* __restrict__ q,
                                              u16* __restrict__ qb) {
    const int r = blockIdx.x, t = threadIdx.x;
    const float* row = q + (size_t)r * ND;
    float4 a = *(const float4*)(row + t * 8);
    float4 b = *(const float4*)(row + t * 8 + 4);
    if (qb) {
        u16x8 v;
        v[0] = f2bf_rne(a.x); v[1] = f2bf_rne(a.y); v[2] = f2bf_rne(a.z); v[3] = f2bf_rne(a.w);
        v[4] = f2bf_rne(b.x); v[5] = f2bf_rne(b.y); v[6] = f2bf_rne(b.z); v[7] = f2bf_rne(b.w);
        *(u16x8*)(qb + (size_t)r * ND + t * 8) = v;
    }
    float ss = a.x*a.x + a.y*a.y + a.z*a.z + a.w*a.w
             + b.x*b.x + b.y*b.y + b.z*b.z + b.w*b.w;
    for (int off = 32; off; off >>= 1) ss += __shfl_xor(ss, off);
    __shared__ float red[4];
    if ((t & 63) == 0) red[t >> 6] = ss;
    __syncthreads();
    if (t == 0) g_qn[r] = sqrtf(red[0] + red[1] + red[2] + red[3]);
}

__global__ __launch_bounds__(256) void prep_k(const float* __restrict__ k,
                                              u16* __restrict__ kb) {
    const int r = blockIdx.x, t = threadIdx.x;
    const float* row = k + (size_t)r * ND;
    float4 a = *(const float4*)(row + t * 8);
    float4 b = *(const float4*)(row + t * 8 + 4);
    if (kb) {
        u16x8 v;
        v[0] = f2bf_rne(a.x); v[1] = f2bf_rne(a.y); v[2] = f2bf_rne(a.z); v[3] = f2bf_rne(a.w);
        v[4] = f2bf_rne(b.x); v[5] = f2bf_rne(b.y); v[6] = f2bf_rne(b.z); v[7] = f2bf_rne(b.w);
        *(u16x8*)(kb + (size_t)r * ND + t * 8) = v;
    }
    float ss = a.x*a.x + a.y*a.y + a.z*a.z + a.w*a.w
             + b.x*b.x + b.y*b.y + b.z*b.z + b.w*b.w;
    for (int off = 32; off; off >>= 1) ss += __shfl_xor(ss, off);
    __shared__ float red[4];
    if ((t & 63) == 0) red[t >> 6] = ss;
    __syncthreads();
    if (t == 0) g_knf[r] = sqrtf(red[0] + red[1] + red[2] + red[3]);
}

// ---------------- GEMM fast: bf16 planes + global_load_lds ----------------

__global__ __launch_bounds__(256) void gemm_fast(const u16* __restrict__ A,
                                                 const u16* __restrict__ B,
                                                 float* __restrict__ C) {
    __shared__ u16 As[128 * 64];
    __shared__ u16 Bs[128 * 64];
    const int t = threadIdx.x, w = t >> 6, l = t & 63;
    const int bid = blockIdx.x;
    const int m0 = (bid >> 3) << 7, n0 = (bid & 7) << 7;
    const int wr = w >> 1, wc = w & 1;

    f32x4 acc[4][4];
#pragma unroll
    for (int m = 0; m < 4; m++)
#pragma unroll
        for (int n = 0; n < 4; n++) acc[m][n] = (f32x4){0.f, 0.f, 0.f, 0.f};

    const int rowi = l >> 3, col8 = l & 7;
    const u16* Abase = A + (size_t)(m0 + w * 8 + rowi) * ND + col8 * 8;
    const u16* Bbase = B + (size_t)(n0 + w * 8 + rowi) * ND + col8 * 8;

    for (int k0 = 0; k0 < ND; k0 += 64) {
#pragma unroll
        for (int i = 0; i < 4; i++) {
            __builtin_amdgcn_global_load_lds(
                (const __attribute__((address_space(1))) void*)(Abase + (size_t)(i * 32) * ND + k0),
                (__attribute__((address_space(3))) void*)(&As[(i * 4 + w) * 512]),
                16, 0, 0);
            __builtin_amdgcn_global_load_lds(
                (const __attribute__((address_space(1))) void*)(Bbase + (size_t)(i * 32) * ND + k0),
                (__attribute__((address_space(3))) void*)(&Bs[(i * 4 + w) * 512]),
                16, 0, 0);
        }
        __syncthreads();
#pragma unroll
        for (int kk = 0; kk < 64; kk += 32) {
            bf16x8 af[4], bfr[4];
#pragma unroll
            for (int m = 0; m < 4; m++)
                af[m] = *(const bf16x8*)&As[(wr * 64 + m * 16 + (l & 15)) * 64 + kk + (l >> 4) * 8];
#pragma unroll
            for (int n = 0; n < 4; n++)
                bfr[n] = *(const bf16x8*)&Bs[(wc * 64 + n * 16 + (l & 15)) * 64 + kk + (l >> 4) * 8];
#pragma unroll
            for (int m = 0; m < 4; m++)
#pragma unroll
                for (int n = 0; n < 4; n++)
                    acc[m][n] = __builtin_amdgcn_mfma_f32_16x16x32_bf16(af[m], bfr[n], acc[m][n], 0, 0, 0);
        }
        __syncthreads();
    }

    const int lc = l & 15, lr4 = (l >> 4) * 4;
#pragma unroll
    for (int m = 0; m < 4; m++) {
        int rbase = m0 + wr * 64 + m * 16 + lr4;
#pragma unroll
        for (int n = 0; n < 4; n++) {
            int col = n0 + wc * 64 + n * 16 + lc;
#pragma unroll
            for (int r = 0; r < 4; r++)
                C[(size_t)(rbase + r) * NP + col] = acc[m][n][r];
        }
    }
}

// ---------------- GEMM slow: f32 inputs, convert during LDS staging ----------------

__global__ __launch_bounds__(256) void gemm_slow(const float* __restrict__ A,
                                                 const float* __restrict__ B,
                                                 float* __restrict__ C) {
    __shared__ u16 As[128 * 64];
    __shared__ u16 Bs[128 * 64];
    const int t = threadIdx.x, w = t >> 6, l = t & 63;
    const int bid = blockIdx.x;
    const int m0 = (bid >> 3) << 7, n0 = (bid & 7) << 7;
    const int wr = w >> 1, wc = w & 1;

    f32x4 acc[4][4];
#pragma unroll
    for (int m = 0; m < 4; m++)
#pragma unroll
        for (int n = 0; n < 4; n++) acc[m][n] = (f32x4){0.f, 0.f, 0.f, 0.f};

    const int arow = t >> 4;
    const int acol4 = t & 15;

    for (int k0 = 0; k0 < ND; k0 += 64) {
#pragma unroll
        for (int s = 0; s < 8; s++) {
            int row = s * 16 + arow;
            float4 va = *(const float4*)(A + (size_t)(m0 + row) * ND + k0 + acol4 * 4);
            u16x4 ba;
            ba[0] = f2bf_rne(va.x); ba[1] = f2bf_rne(va.y);
            ba[2] = f2bf_rne(va.z); ba[3] = f2bf_rne(va.w);
            *(u16x4*)&As[row * 64 + acol4 * 4] = ba;
            float4 vb = *(const float4*)(B + (size_t)(n0 + row) * ND + k0 + acol4 * 4);
            u16x4 bb;
            bb[0] = f2bf_rne(vb.x); bb[1] = f2bf_rne(vb.y);
            bb[2] = f2bf_rne(vb.z); bb[3] = f2bf_rne(vb.w);
            *(u16x4*)&Bs[row * 64 + acol4 * 4] = bb;
        }
        __syncthreads();
#pragma unroll
        for (int kk = 0; kk < 64; kk += 32) {
            bf16x8 af[4], bfr[4];
#pragma unroll
            for (int m = 0; m < 4; m++)
                af[m] = *(const bf16x8*)&As[(wr * 64 + m * 16 + (l & 15)) * 64 + kk + (l >> 4) * 8];
#pragma unroll
            for (int n = 0; n < 4; n++)
                bfr[n] = *(const bf16x8*)&Bs[(wc * 64 + n * 16 + (l & 15)) * 64 + kk + (l >> 4) * 8];
#pragma unroll
            for (int m = 0; m < 4; m++)
#pragma unroll
                for (int n = 0; n < 4; n++)
                    acc[m][n] = __builtin_amdgcn_mfma_f32_16x16x32_bf16(af[m], bfr[n], acc[m][n], 0, 0, 0);
        }
        __syncthreads();
    }

    const int lc = l & 15, lr4 = (l >> 4) * 4;
#pragma unroll
    for (int m = 0; m < 4; m++) {
        int rbase = m0 + wr * 64 + m * 16 + lr4;
#pragma unroll
        for (int n = 0; n < 4; n++) {
            int col = n0 + wc * 64 + n * 16 + lc;
#pragma unroll
            for (int r = 0; r < 4; r++)
                C[(size_t)(rbase + r) * NP + col] = acc[m][n][r];
        }
    }
}

// ---------------- per-row: entropy + top-5 -> per-row partials (NO atomics) ----------------
// 256 threads = 4 waves = 4 independent rows per block.

__global__ __launch_bounds__(256) void rowstats(const float* __restrict__ C) {
    const int l = threadIdx.x & 63;
    const int r = blockIdx.x * 4 + (threadIdx.x >> 6);
    const float qn = g_qn[r];

    const float* crow = C + (size_t)r * NP;
    float s[16];
#pragma unroll
    for (int j = 0; j < 16; j++) {
        float dot = crow[j * 64 + l];
        float kn = g_knf[j * 64 + l];
        s[j] = 1.0f - dot / fmaxf(qn * kn, 1e-8f);
    }

    // entropy of softmax(s): ln(S0) - S1/S0 with d = s - max
    float mx = s[0];
#pragma unroll
    for (int j = 1; j < 16; j++) mx = fmaxf(mx, s[j]);
    for (int off = 32; off; off >>= 1) mx = fmaxf(mx, __shfl_xor(mx, off));
    float S0 = 0.f, S1 = 0.f;
#pragma unroll
    for (int j = 0; j < 16; j++) {
        float d = s[j] - mx;
        float e = __expf(d);
        S0 += e;
        S1 += d * e;
    }
    for (int off = 32; off; off >>= 1) {
        S0 += __shfl_xor(S0, off);
        S1 += __shfl_xor(S1, off);
    }

    // top-5 smallest s, tie-break = smallest index (top_k first-occurrence)
    unsigned used = 0;
    float ssum = 0.f;
    int ci[KSEL];
    for (int i = 0; i < KSEL; i++) {
        float bv = 3.0e38f;
        int bp = 0;
#pragma unroll
        for (int j = 0; j < 16; j++) {
            if (!((used >> j) & 1) && s[j] < bv) { bv = s[j]; bp = j * 64 + l; }
        }
        u64 u = ((u64)__float_as_uint(bv) << 32) | (u32)bp;
        for (int off = 32; off; off >>= 1) {
            u64 o = __shfl_xor(u, off);
            if (o < u) u = o;
        }
        int p = (int)(u & 0xffffffffu);
        ci[i] = p;
        ssum += __uint_as_float((u32)(u >> 32));
        if ((p & 63) == l) used |= 1u << (p >> 6);
    }
    if (l == 0) {
        g_pent[r] = logf(S0) - S1 / S0;
        g_psel[r] = ssum;
#pragma unroll
        for (int i = 0; i < KSEL; i++) g_cidx[r * 8 + i] = ci[i];
    }
}

// ---------------- gather + f32 output ----------------

__global__ __launch_bounds__(256) void gather_out(const float* __restrict__ ppg,
                                                  const float* __restrict__ prompt,
                                                  float* __restrict__ outp) {
    const int r = blockIdx.x, t = threadIdx.x;
    __shared__ int sel[KSEL];
    if (t < KSEL) sel[t] = g_cidx[r * 8 + t];
    __syncthreads();

    const float* prow = ppg + (size_t)r * ND + t * 8;
    float4 a = *(const float4*)prow;
    float4 b = *(const float4*)(prow + 4);
    float4 ax = {0, 0, 0, 0}, bx = {0, 0, 0, 0};
#pragma unroll
    for (int i = 0; i < KSEL; i++) {
        const float* pr = prompt + (size_t)sel[i] * ND + t * 8;
        float4 x = *(const float4*)pr;
        float4 y = *(const float4*)(pr + 4);
        ax.x += x.x; ax.y += x.y; ax.z += x.z; ax.w += x.w;
        bx.x += y.x; bx.y += y.y; bx.z += y.z; bx.w += y.w;
    }
    float4 oa = {a.x + 0.5f * ax.x, a.y + 0.5f * ax.y, a.z + 0.5f * ax.z, a.w + 0.5f * ax.w};
    float4 ob = {b.x + 0.5f * bx.x, b.y + 0.5f * bx.y, b.z + 0.5f * bx.z, b.w + 0.5f * bx.w};
    float* orow = outp + (size_t)r * ND + t * 8;
    *(float4*)orow = oa;
    *(float4*)(orow + 4) = ob;
}

// ---------------- reduce per-row partials -> the two scalar outputs ----------------

__global__ __launch_bounds__(1024) void finalize_scal(float* __restrict__ outp) {
    const int t = threadIdx.x;
    float a = 0.f, b = 0.f;
#pragma unroll
    for (int i = 0; i < NB / 1024; i++) {
        a += g_psel[i * 1024 + t];
        b += g_pent[i * 1024 + t];
    }
    for (int off = 32; off; off >>= 1) {
        a += __shfl_xor(a, off);
        b += __shfl_xor(b, off);
    }
    __shared__ float ra[16], rb[16];
    if ((t & 63) == 0) { ra[t >> 6] = a; rb[t >> 6] = b; }
    __syncthreads();
    if (t == 0) {
        float sa = 0.f, sb = 0.f;
#pragma unroll
        for (int i = 0; i < 16; i++) { sa += ra[i]; sb += rb[i]; }
        outp[(size_t)NB * ND] = sa;
        outp[(size_t)NB * ND + 1] = sb;
    }
}

extern "C" void kernel_launch(void* const* d_in, const int* in_sizes, int n_in,
                              void* d_out, int out_size, void* d_ws, size_t ws_size,
                              hipStream_t stream) {
    const float* ppg    = (const float*)d_in[0];
    const float* keys   = (const float*)d_in[1];
    const float* prompt = (const float*)d_in[2];
    float* outp = (float*)d_out;

    // 32MB f32 dot matrix lives in d_out [0 : NB*NP): gemm writes, rowstats
    // consumes, gather_out overwrites (stream-ordered).
    float* C = (float*)d_out;

    const size_t QB_BYTES = (size_t)NB * ND * 2;
    const size_t KB_BYTES = (size_t)NP * ND * 2;
    bool fast = (d_ws != nullptr) && (ws_size >= QB_BYTES + KB_BYTES);
    u16* qb = fast ? (u16*)d_ws : nullptr;
    u16* kb = fast ? (u16*)((char*)d_ws + QB_BYTES) : nullptr;

    prep_q<<<NB, 256, 0, stream>>>(ppg, qb);    // always: computes g_qn
    prep_k<<<NP, 256, 0, stream>>>(keys, kb);   // always: computes g_knf
    if (fast) {
        gemm_fast<<<(NB / 128) * (NP / 128), 256, 0, stream>>>(qb, kb, C);
    } else {
        gemm_slow<<<(NB / 128) * (NP / 128), 256, 0, stream>>>(ppg, keys, C);
    }
    rowstats<<<NB / 4, 256, 0, stream>>>(C);
    gather_out<<<NB, 256, 0, stream>>>(ppg, prompt, outp);
    finalize_scal<<<1, 1024, 0, stream>>>(outp);
}

// Round 6
// 235.320 us; speedup vs baseline: 1.9107x; 1.0451x over previous
//
#include <hip/hip_runtime.h>
#include <stdint.h>

#define NB 8192
#define NP 1024
#define ND 2048
#define KSEL 5

typedef unsigned short u16;
typedef unsigned int u32;
typedef unsigned long long u64;
typedef __attribute__((ext_vector_type(8))) short bf16x8;
typedef __attribute__((ext_vector_type(8))) u16 u16x8;
typedef __attribute__((ext_vector_type(4))) u16 u16x4;
typedef __attribute__((ext_vector_type(4))) float f32x4;

// Output is FLOAT32. ws_size >= 37.75MB confirmed (gemm_fast ran in round-5 profile).
// Round-5: gemm occupancy 17.8% (512 blocks = 2/CU) -> 8-wave blocks; FETCH 133MB
// -> XCD-bijective swizzle; rowstats+gather fused; C is bf16 in __device__ global.
__device__ float g_knf[NP];
__device__ float g_qn[NB];
__device__ float g_psel[NB];
__device__ float g_pent[NB];
__device__ u16   g_C[(size_t)NB * NP];   // bf16 s = 1 - cos

__device__ __forceinline__ u16 f2bf_rne(float f) {
    u32 u = __float_as_uint(f);
    u = (u + 0x7fffu + ((u >> 16) & 1u)) >> 16;
    return (u16)u;
}
__device__ __forceinline__ float bf2f(u16 v) {
    return __uint_as_float(((u32)v) << 16);
}

// ---------------- prep: f32 -> bf16 planes + norms (q and k fused) ----------------

__global__ __launch_bounds__(256) void prep(const float* __restrict__ q,
                                            const float* __restrict__ k,
                                            u16* __restrict__ qb,
                                            u16* __restrict__ kb) {
    const int rr = blockIdx.x, t = threadIdx.x;
    const float* row;
    u16* dst;
    if (rr < NB) {
        row = q + (size_t)rr * ND;
        dst = qb ? qb + (size_t)rr * ND : nullptr;
    } else {
        row = k + (size_t)(rr - NB) * ND;
        dst = kb ? kb + (size_t)(rr - NB) * ND : nullptr;
    }
    float4 a = *(const float4*)(row + t * 8);
    float4 b = *(const float4*)(row + t * 8 + 4);
    if (dst) {
        u16x8 v;
        v[0] = f2bf_rne(a.x); v[1] = f2bf_rne(a.y); v[2] = f2bf_rne(a.z); v[3] = f2bf_rne(a.w);
        v[4] = f2bf_rne(b.x); v[5] = f2bf_rne(b.y); v[6] = f2bf_rne(b.z); v[7] = f2bf_rne(b.w);
        *(u16x8*)(dst + t * 8) = v;
    }
    float ss = a.x*a.x + a.y*a.y + a.z*a.z + a.w*a.w
             + b.x*b.x + b.y*b.y + b.z*b.z + b.w*b.w;
    for (int off = 32; off; off >>= 1) ss += __shfl_xor(ss, off);
    __shared__ float red[4];
    if ((t & 63) == 0) red[t >> 6] = ss;
    __syncthreads();
    if (t == 0) {
        float n = sqrtf(red[0] + red[1] + red[2] + red[3]);
        if (rr < NB) g_qn[rr] = n; else g_knf[rr - NB] = n;
    }
}

// ---------------- GEMM fast: 128x128 tile, 8 waves, XCD swizzle, bf16-s epilogue ----------------

__global__ __launch_bounds__(512, 4) void gemm_fast(const u16* __restrict__ A,
                                                    const u16* __restrict__ B) {
    __shared__ u16 As[128 * 64];
    __shared__ u16 Bs[128 * 64];
    const int t = threadIdx.x, w = t >> 6, l = t & 63;
    // XCD-bijective swizzle: xcd = bid%8 owns A-panel rows [xcd*1024, +1024)
    const int bid = blockIdx.x;
    const int xcd = bid & 7, j = bid >> 3;         // j in [0,64)
    const int m0 = (xcd * 8 + (j & 7)) << 7;       // m-block 0..63
    const int n0 = (j >> 3) << 7;                  // n-block 0..7
    const int wr = w >> 1, wc = w & 1;             // wr 0..3, wc 0..1

    f32x4 acc[2][4];
#pragma unroll
    for (int m = 0; m < 2; m++)
#pragma unroll
        for (int n = 0; n < 4; n++) acc[m][n] = (f32x4){0.f, 0.f, 0.f, 0.f};

    const int rt = t >> 3, c8 = t & 7;             // staging row (0..63), 16B col
    const u16* Abase = A + (size_t)(m0 + rt) * ND + c8 * 8;
    const u16* Bbase = B + (size_t)(n0 + rt) * ND + c8 * 8;

    for (int k0 = 0; k0 < ND; k0 += 64) {
#pragma unroll
        for (int i = 0; i < 2; i++) {
            __builtin_amdgcn_global_load_lds(
                (const __attribute__((address_space(1))) void*)(Abase + (size_t)(i * 64) * ND + k0),
                (__attribute__((address_space(3))) void*)(&As[i * 4096 + w * 512]),
                16, 0, 0);
            __builtin_amdgcn_global_load_lds(
                (const __attribute__((address_space(1))) void*)(Bbase + (size_t)(i * 64) * ND + k0),
                (__attribute__((address_space(3))) void*)(&Bs[i * 4096 + w * 512]),
                16, 0, 0);
        }
        __syncthreads();
#pragma unroll
        for (int kk = 0; kk < 64; kk += 32) {
            bf16x8 af[2], bfr[4];
#pragma unroll
            for (int m = 0; m < 2; m++)
                af[m] = *(const bf16x8*)&As[(wr * 32 + m * 16 + (l & 15)) * 64 + kk + (l >> 4) * 8];
#pragma unroll
            for (int n = 0; n < 4; n++)
                bfr[n] = *(const bf16x8*)&Bs[(wc * 64 + n * 16 + (l & 15)) * 64 + kk + (l >> 4) * 8];
#pragma unroll
            for (int m = 0; m < 2; m++)
#pragma unroll
                for (int n = 0; n < 4; n++)
                    acc[m][n] = __builtin_amdgcn_mfma_f32_16x16x32_bf16(af[m], bfr[n], acc[m][n], 0, 0, 0);
        }
        __syncthreads();
    }

    const int lc = l & 15, lr4 = (l >> 4) * 4;
#pragma unroll
    for (int m = 0; m < 2; m++) {
        int rbase = m0 + wr * 32 + m * 16 + lr4;
#pragma unroll
        for (int n = 0; n < 4; n++) {
            int col = n0 + wc * 64 + n * 16 + lc;
            float kn = g_knf[col];
#pragma unroll
            for (int r = 0; r < 4; r++) {
                int row = rbase + r;
                float s = 1.0f - acc[m][n][r] / fmaxf(g_qn[row] * kn, 1e-8f);
                g_C[(size_t)row * NP + col] = f2bf_rne(s);
            }
        }
    }
}

// ---------------- GEMM slow (fallback, ws too small): convert during staging ----------------

__global__ __launch_bounds__(256) void gemm_slow(const float* __restrict__ A,
                                                 const float* __restrict__ B) {
    __shared__ u16 As[128 * 64];
    __shared__ u16 Bs[128 * 64];
    const int t = threadIdx.x, w = t >> 6, l = t & 63;
    const int bid = blockIdx.x;
    const int m0 = (bid >> 3) << 7, n0 = (bid & 7) << 7;
    const int wr = w >> 1, wc = w & 1;

    f32x4 acc[4][4];
#pragma unroll
    for (int m = 0; m < 4; m++)
#pragma unroll
        for (int n = 0; n < 4; n++) acc[m][n] = (f32x4){0.f, 0.f, 0.f, 0.f};

    const int arow = t >> 4, acol4 = t & 15;

    for (int k0 = 0; k0 < ND; k0 += 64) {
#pragma unroll
        for (int s = 0; s < 8; s++) {
            int row = s * 16 + arow;
            float4 va = *(const float4*)(A + (size_t)(m0 + row) * ND + k0 + acol4 * 4);
            u16x4 ba;
            ba[0] = f2bf_rne(va.x); ba[1] = f2bf_rne(va.y);
            ba[2] = f2bf_rne(va.z); ba[3] = f2bf_rne(va.w);
            *(u16x4*)&As[row * 64 + acol4 * 4] = ba;
            float4 vb = *(const float4*)(B + (size_t)(n0 + row) * ND + k0 + acol4 * 4);
            u16x4 bb;
            bb[0] = f2bf_rne(vb.x); bb[1] = f2bf_rne(vb.y);
            bb[2] = f2bf_rne(vb.z); bb[3] = f2bf_rne(vb.w);
            *(u16x4*)&Bs[row * 64 + acol4 * 4] = bb;
        }
        __syncthreads();
#pragma unroll
        for (int kk = 0; kk < 64; kk += 32) {
            bf16x8 af[4], bfr[4];
#pragma unroll
            for (int m = 0; m < 4; m++)
                af[m] = *(const bf16x8*)&As[(wr * 64 + m * 16 + (l & 15)) * 64 + kk + (l >> 4) * 8];
#pragma unroll
            for (int n = 0; n < 4; n++)
                bfr[n] = *(const bf16x8*)&Bs[(wc * 64 + n * 16 + (l & 15)) * 64 + kk + (l >> 4) * 8];
#pragma unroll
            for (int m = 0; m < 4; m++)
#pragma unroll
                for (int n = 0; n < 4; n++)
                    acc[m][n] = __builtin_amdgcn_mfma_f32_16x16x32_bf16(af[m], bfr[n], acc[m][n], 0, 0, 0);
        }
        __syncthreads();
    }

    const int lc = l & 15, lr4 = (l >> 4) * 4;
#pragma unroll
    for (int m = 0; m < 4; m++) {
        int rbase = m0 + wr * 64 + m * 16 + lr4;
#pragma unroll
        for (int n = 0; n < 4; n++) {
            int col = n0 + wc * 64 + n * 16 + lc;
            float kn = g_knf[col];
#pragma unroll
            for (int r = 0; r < 4; r++) {
                int row = rbase + r;
                float s = 1.0f - acc[m][n][r] / fmaxf(g_qn[row] * kn, 1e-8f);
                g_C[(size_t)row * NP + col] = f2bf_rne(s);
            }
        }
    }
}

// ---------------- post: entropy + top-5 + gather + output, one wave per row ----------------

__global__ __launch_bounds__(64) void post(const float* __restrict__ ppg,
                                           const float* __restrict__ prompt,
                                           float* __restrict__ outp) {
    const int r = blockIdx.x, l = threadIdx.x;

    // lane l holds s indices [l*16, l*16+16)
    u16x8 v0 = *(const u16x8*)&g_C[(size_t)r * NP + l * 16];
    u16x8 v1 = *(const u16x8*)&g_C[(size_t)r * NP + l * 16 + 8];
    float s[16];
#pragma unroll
    for (int j = 0; j < 8; j++) { s[j] = bf2f(v0[j]); s[8 + j] = bf2f(v1[j]); }

    // entropy of softmax(s): ln(S0) - S1/S0, d = s - max
    float mx = s[0];
#pragma unroll
    for (int j = 1; j < 16; j++) mx = fmaxf(mx, s[j]);
    for (int off = 32; off; off >>= 1) mx = fmaxf(mx, __shfl_xor(mx, off));
    float S0 = 0.f, S1 = 0.f;
#pragma unroll
    for (int j = 0; j < 16; j++) {
        float d = s[j] - mx;
        float e = __expf(d);
        S0 += e;
        S1 += d * e;
    }
    for (int off = 32; off; off >>= 1) {
        S0 += __shfl_xor(S0, off);
        S1 += __shfl_xor(S1, off);
    }

    // top-5 smallest s, tie-break smallest index (top_k first-occurrence)
    unsigned used = 0;
    float ssum = 0.f;
    int sel[KSEL];
    for (int i = 0; i < KSEL; i++) {
        float bv = 3.0e38f;
        int bp = 0;
#pragma unroll
        for (int j = 0; j < 16; j++) {
            if (!((used >> j) & 1) && s[j] < bv) { bv = s[j]; bp = l * 16 + j; }
        }
        u64 u = ((u64)__float_as_uint(bv) << 32) | (u32)bp;
        for (int off = 32; off; off >>= 1) {
            u64 o = __shfl_xor(u, off);
            if (o < u) u = o;
        }
        int p = (int)(u & 0xffffffffu);
        sel[i] = p;
        ssum += __uint_as_float((u32)(u >> 32));
        if ((p >> 4) == l) used |= 1u << (p & 15);
    }
    if (l == 0) {
        g_pent[r] = logf(S0) - S1 / S0;
        g_psel[r] = ssum;
    }

    // gather + output: 2048 floats = 8 float4 per lane
    const float* prow = ppg + (size_t)r * ND;
    float* orow = outp + (size_t)r * ND;
    const float* p0 = prompt + (size_t)sel[0] * ND;
    const float* p1 = prompt + (size_t)sel[1] * ND;
    const float* p2 = prompt + (size_t)sel[2] * ND;
    const float* p3 = prompt + (size_t)sel[3] * ND;
    const float* p4 = prompt + (size_t)sel[4] * ND;
#pragma unroll
    for (int j = 0; j < 8; j++) {
        int o = (j * 64 + l) * 4;
        float4 a = *(const float4*)(prow + o);
        float4 x0 = *(const float4*)(p0 + o);
        float4 x1 = *(const float4*)(p1 + o);
        float4 x2 = *(const float4*)(p2 + o);
        float4 x3 = *(const float4*)(p3 + o);
        float4 x4 = *(const float4*)(p4 + o);
        float4 res;
        res.x = a.x + 0.5f * (x0.x + x1.x + x2.x + x3.x + x4.x);
        res.y = a.y + 0.5f * (x0.y + x1.y + x2.y + x3.y + x4.y);
        res.z = a.z + 0.5f * (x0.z + x1.z + x2.z + x3.z + x4.z);
        res.w = a.w + 0.5f * (x0.w + x1.w + x2.w + x3.w + x4.w);
        *(float4*)(orow + o) = res;
    }
}

// ---------------- reduce per-row partials -> two scalar outputs ----------------

__global__ __launch_bounds__(1024) void finalize_scal(float* __restrict__ outp) {
    const int t = threadIdx.x;
    float a = 0.f, b = 0.f;
#pragma unroll
    for (int i = 0; i < NB / 1024; i++) {
        a += g_psel[i * 1024 + t];
        b += g_pent[i * 1024 + t];
    }
    for (int off = 32; off; off >>= 1) {
        a += __shfl_xor(a, off);
        b += __shfl_xor(b, off);
    }
    __shared__ float ra[16], rb[16];
    if ((t & 63) == 0) { ra[t >> 6] = a; rb[t >> 6] = b; }
    __syncthreads();
    if (t == 0) {
        float sa = 0.f, sb = 0.f;
#pragma unroll
        for (int i = 0; i < 16; i++) { sa += ra[i]; sb += rb[i]; }
        outp[(size_t)NB * ND] = sa;
        outp[(size_t)NB * ND + 1] = sb;
    }
}

extern "C" void kernel_launch(void* const* d_in, const int* in_sizes, int n_in,
                              void* d_out, int out_size, void* d_ws, size_t ws_size,
                              hipStream_t stream) {
    const float* ppg    = (const float*)d_in[0];
    const float* keys   = (const float*)d_in[1];
    const float* prompt = (const float*)d_in[2];
    float* outp = (float*)d_out;

    const size_t QB_BYTES = (size_t)NB * ND * 2;
    const size_t KB_BYTES = (size_t)NP * ND * 2;
    bool fast = (d_ws != nullptr) && (ws_size >= QB_BYTES + KB_BYTES);
    u16* qb = fast ? (u16*)d_ws : nullptr;
    u16* kb = fast ? (u16*)((char*)d_ws + QB_BYTES) : nullptr;

    prep<<<NB + NP, 256, 0, stream>>>(ppg, keys, qb, kb);
    if (fast) {
        gemm_fast<<<512, 512, 0, stream>>>(qb, kb);
    } else {
        gemm_slow<<<512, 256, 0, stream>>>(ppg, keys);
    }
    post<<<NB, 64, 0, stream>>>(ppg, prompt, outp);
    finalize_scal<<<1, 1024, 0, stream>>>(outp);
}

// Round 7
// 230.277 us; speedup vs baseline: 1.9526x; 1.0219x over previous
//
#include <hip/hip_runtime.h>
#include <stdint.h>

#define NB 8192
#define NP 1024
#define ND 2048
#define KSEL 5

typedef unsigned short u16;
typedef unsigned int u32;
typedef unsigned long long u64;
typedef __attribute__((ext_vector_type(8))) short bf16x8;
typedef __attribute__((ext_vector_type(8))) u16 u16x8;
typedef __attribute__((ext_vector_type(4))) u16 u16x4;
typedef __attribute__((ext_vector_type(4))) float f32x4;

// Output is FLOAT32. ws >= 37.75MB confirmed (fast path ran, rounds 5-6).
// Round-6 lesson: 8-wave gemm (acc[2][4]) regressed 57.5->61.5us -- halved
// per-wave MFMA per barrier. Revert to 4-wave acc[4][4] (m97, round-5
// validated) KEEPING round-6's wins: XCD-bijective swizzle (FETCH 133->33MB)
// + fused bf16 s=1-cos epilogue (WRITE 49->16MB).
__device__ float g_knf[NP];
__device__ float g_qn[NB];
__device__ float g_psel[NB];
__device__ float g_pent[NB];
__device__ u16   g_C[(size_t)NB * NP];   // bf16 s = 1 - cos

__device__ __forceinline__ u16 f2bf_rne(float f) {
    u32 u = __float_as_uint(f);
    u = (u + 0x7fffu + ((u >> 16) & 1u)) >> 16;
    return (u16)u;
}
__device__ __forceinline__ float bf2f(u16 v) {
    return __uint_as_float(((u32)v) << 16);
}

// ---------------- prep: f32 -> bf16 planes + norms (q and k fused) ----------------

__global__ __launch_bounds__(256) void prep(const float* __restrict__ q,
                                            const float* __restrict__ k,
                                            u16* __restrict__ qb,
                                            u16* __restrict__ kb) {
    const int rr = blockIdx.x, t = threadIdx.x;
    const float* row;
    u16* dst;
    if (rr < NB) {
        row = q + (size_t)rr * ND;
        dst = qb ? qb + (size_t)rr * ND : nullptr;
    } else {
        row = k + (size_t)(rr - NB) * ND;
        dst = kb ? kb + (size_t)(rr - NB) * ND : nullptr;
    }
    float4 a = *(const float4*)(row + t * 8);
    float4 b = *(const float4*)(row + t * 8 + 4);
    if (dst) {
        u16x8 v;
        v[0] = f2bf_rne(a.x); v[1] = f2bf_rne(a.y); v[2] = f2bf_rne(a.z); v[3] = f2bf_rne(a.w);
        v[4] = f2bf_rne(b.x); v[5] = f2bf_rne(b.y); v[6] = f2bf_rne(b.z); v[7] = f2bf_rne(b.w);
        *(u16x8*)(dst + t * 8) = v;
    }
    float ss = a.x*a.x + a.y*a.y + a.z*a.z + a.w*a.w
             + b.x*b.x + b.y*b.y + b.z*b.z + b.w*b.w;
    for (int off = 32; off; off >>= 1) ss += __shfl_xor(ss, off);
    __shared__ float red[4];
    if ((t & 63) == 0) red[t >> 6] = ss;
    __syncthreads();
    if (t == 0) {
        float n = sqrtf(red[0] + red[1] + red[2] + red[3]);
        if (rr < NB) g_qn[rr] = n; else g_knf[rr - NB] = n;
    }
}

// ---------------- GEMM fast: m97 4-wave 128x128, XCD swizzle, bf16-s epilogue ----------------

__global__ __launch_bounds__(256) void gemm_fast(const u16* __restrict__ A,
                                                 const u16* __restrict__ B) {
    __shared__ u16 As[128 * 64];
    __shared__ u16 Bs[128 * 64];
    const int t = threadIdx.x, w = t >> 6, l = t & 63;
    // XCD-bijective swizzle (512 % 8 == 0): xcd = bid&7 owns m-blocks [xcd*8, +8)
    const int bid = blockIdx.x;
    const int xcd = bid & 7, j = bid >> 3;     // j in [0,64)
    const int m0 = (xcd * 8 + (j & 7)) << 7;   // m-block 0..63
    const int n0 = (j >> 3) << 7;              // n-block 0..7
    const int wr = w >> 1, wc = w & 1;

    f32x4 acc[4][4];
#pragma unroll
    for (int m = 0; m < 4; m++)
#pragma unroll
        for (int n = 0; n < 4; n++) acc[m][n] = (f32x4){0.f, 0.f, 0.f, 0.f};

    const int rowi = l >> 3, col8 = l & 7;
    const u16* Abase = A + (size_t)(m0 + w * 8 + rowi) * ND + col8 * 8;
    const u16* Bbase = B + (size_t)(n0 + w * 8 + rowi) * ND + col8 * 8;

    for (int k0 = 0; k0 < ND; k0 += 64) {
#pragma unroll
        for (int i = 0; i < 4; i++) {
            __builtin_amdgcn_global_load_lds(
                (const __attribute__((address_space(1))) void*)(Abase + (size_t)(i * 32) * ND + k0),
                (__attribute__((address_space(3))) void*)(&As[(i * 4 + w) * 512]),
                16, 0, 0);
            __builtin_amdgcn_global_load_lds(
                (const __attribute__((address_space(1))) void*)(Bbase + (size_t)(i * 32) * ND + k0),
                (__attribute__((address_space(3))) void*)(&Bs[(i * 4 + w) * 512]),
                16, 0, 0);
        }
        __syncthreads();
#pragma unroll
        for (int kk = 0; kk < 64; kk += 32) {
            bf16x8 af[4], bfr[4];
#pragma unroll
            for (int m = 0; m < 4; m++)
                af[m] = *(const bf16x8*)&As[(wr * 64 + m * 16 + (l & 15)) * 64 + kk + (l >> 4) * 8];
#pragma unroll
            for (int n = 0; n < 4; n++)
                bfr[n] = *(const bf16x8*)&Bs[(wc * 64 + n * 16 + (l & 15)) * 64 + kk + (l >> 4) * 8];
#pragma unroll
            for (int m = 0; m < 4; m++)
#pragma unroll
                for (int n = 0; n < 4; n++)
                    acc[m][n] = __builtin_amdgcn_mfma_f32_16x16x32_bf16(af[m], bfr[n], acc[m][n], 0, 0, 0);
        }
        __syncthreads();
    }

    const int lc = l & 15, lr4 = (l >> 4) * 4;
#pragma unroll
    for (int m = 0; m < 4; m++) {
        int rbase = m0 + wr * 64 + m * 16 + lr4;
#pragma unroll
        for (int n = 0; n < 4; n++) {
            int col = n0 + wc * 64 + n * 16 + lc;
            float kn = g_knf[col];
#pragma unroll
            for (int r = 0; r < 4; r++) {
                int row = rbase + r;
                float s = 1.0f - acc[m][n][r] / fmaxf(g_qn[row] * kn, 1e-8f);
                g_C[(size_t)row * NP + col] = f2bf_rne(s);
            }
        }
    }
}

// ---------------- GEMM slow (fallback, ws too small): convert during staging ----------------

__global__ __launch_bounds__(256) void gemm_slow(const float* __restrict__ A,
                                                 const float* __restrict__ B) {
    __shared__ u16 As[128 * 64];
    __shared__ u16 Bs[128 * 64];
    const int t = threadIdx.x, w = t >> 6, l = t & 63;
    const int bid = blockIdx.x;
    const int xcd = bid & 7, j = bid >> 3;
    const int m0 = (xcd * 8 + (j & 7)) << 7;
    const int n0 = (j >> 3) << 7;
    const int wr = w >> 1, wc = w & 1;

    f32x4 acc[4][4];
#pragma unroll
    for (int m = 0; m < 4; m++)
#pragma unroll
        for (int n = 0; n < 4; n++) acc[m][n] = (f32x4){0.f, 0.f, 0.f, 0.f};

    const int arow = t >> 4, acol4 = t & 15;

    for (int k0 = 0; k0 < ND; k0 += 64) {
#pragma unroll
        for (int s = 0; s < 8; s++) {
            int row = s * 16 + arow;
            float4 va = *(const float4*)(A + (size_t)(m0 + row) * ND + k0 + acol4 * 4);
            u16x4 ba;
            ba[0] = f2bf_rne(va.x); ba[1] = f2bf_rne(va.y);
            ba[2] = f2bf_rne(va.z); ba[3] = f2bf_rne(va.w);
            *(u16x4*)&As[row * 64 + acol4 * 4] = ba;
            float4 vb = *(const float4*)(B + (size_t)(n0 + row) * ND + k0 + acol4 * 4);
            u16x4 bb;
            bb[0] = f2bf_rne(vb.x); bb[1] = f2bf_rne(vb.y);
            bb[2] = f2bf_rne(vb.z); bb[3] = f2bf_rne(vb.w);
            *(u16x4*)&Bs[row * 64 + acol4 * 4] = bb;
        }
        __syncthreads();
#pragma unroll
        for (int kk = 0; kk < 64; kk += 32) {
            bf16x8 af[4], bfr[4];
#pragma unroll
            for (int m = 0; m < 4; m++)
                af[m] = *(const bf16x8*)&As[(wr * 64 + m * 16 + (l & 15)) * 64 + kk + (l >> 4) * 8];
#pragma unroll
            for (int n = 0; n < 4; n++)
                bfr[n] = *(const bf16x8*)&Bs[(wc * 64 + n * 16 + (l & 15)) * 64 + kk + (l >> 4) * 8];
#pragma unroll
            for (int m = 0; m < 4; m++)
#pragma unroll
                for (int n = 0; n < 4; n++)
                    acc[m][n] = __builtin_amdgcn_mfma_f32_16x16x32_bf16(af[m], bfr[n], acc[m][n], 0, 0, 0);
        }
        __syncthreads();
    }

    const int lc = l & 15, lr4 = (l >> 4) * 4;
#pragma unroll
    for (int m = 0; m < 4; m++) {
        int rbase = m0 + wr * 64 + m * 16 + lr4;
#pragma unroll
        for (int n = 0; n < 4; n++) {
            int col = n0 + wc * 64 + n * 16 + lc;
            float kn = g_knf[col];
#pragma unroll
            for (int r = 0; r < 4; r++) {
                int row = rbase + r;
                float s = 1.0f - acc[m][n][r] / fmaxf(g_qn[row] * kn, 1e-8f);
                g_C[(size_t)row * NP + col] = f2bf_rne(s);
            }
        }
    }
}

// ---------------- post: entropy + top-5 + gather + output, one wave per row ----------------

__global__ __launch_bounds__(64) void post(const float* __restrict__ ppg,
                                           const float* __restrict__ prompt,
                                           float* __restrict__ outp) {
    const int r = blockIdx.x, l = threadIdx.x;

    // lane l holds s indices [l*16, l*16+16)
    u16x8 v0 = *(const u16x8*)&g_C[(size_t)r * NP + l * 16];
    u16x8 v1 = *(const u16x8*)&g_C[(size_t)r * NP + l * 16 + 8];
    float s[16];
#pragma unroll
    for (int j = 0; j < 8; j++) { s[j] = bf2f(v0[j]); s[8 + j] = bf2f(v1[j]); }

    // entropy of softmax(s): ln(S0) - S1/S0, d = s - max
    float mx = s[0];
#pragma unroll
    for (int j = 1; j < 16; j++) mx = fmaxf(mx, s[j]);
    for (int off = 32; off; off >>= 1) mx = fmaxf(mx, __shfl_xor(mx, off));
    float S0 = 0.f, S1 = 0.f;
#pragma unroll
    for (int j = 0; j < 16; j++) {
        float d = s[j] - mx;
        float e = __expf(d);
        S0 += e;
        S1 += d * e;
    }
    for (int off = 32; off; off >>= 1) {
        S0 += __shfl_xor(S0, off);
        S1 += __shfl_xor(S1, off);
    }

    // top-5 smallest s, tie-break smallest index (top_k first-occurrence)
    unsigned used = 0;
    float ssum = 0.f;
    int sel[KSEL];
    for (int i = 0; i < KSEL; i++) {
        float bv = 3.0e38f;
        int bp = 0;
#pragma unroll
        for (int j = 0; j < 16; j++) {
            if (!((used >> j) & 1) && s[j] < bv) { bv = s[j]; bp = l * 16 + j; }
        }
        u64 u = ((u64)__float_as_uint(bv) << 32) | (u32)bp;
        for (int off = 32; off; off >>= 1) {
            u64 o = __shfl_xor(u, off);
            if (o < u) u = o;
        }
        int p = (int)(u & 0xffffffffu);
        sel[i] = p;
        ssum += __uint_as_float((u32)(u >> 32));
        if ((p >> 4) == l) used |= 1u << (p & 15);
    }
    if (l == 0) {
        g_pent[r] = logf(S0) - S1 / S0;
        g_psel[r] = ssum;
    }

    // gather + output: 2048 floats = 8 float4 per lane
    const float* prow = ppg + (size_t)r * ND;
    float* orow = outp + (size_t)r * ND;
    const float* p0 = prompt + (size_t)sel[0] * ND;
    const float* p1 = prompt + (size_t)sel[1] * ND;
    const float* p2 = prompt + (size_t)sel[2] * ND;
    const float* p3 = prompt + (size_t)sel[3] * ND;
    const float* p4 = prompt + (size_t)sel[4] * ND;
#pragma unroll
    for (int j = 0; j < 8; j++) {
        int o = (j * 64 + l) * 4;
        float4 a = *(const float4*)(prow + o);
        float4 x0 = *(const float4*)(p0 + o);
        float4 x1 = *(const float4*)(p1 + o);
        float4 x2 = *(const float4*)(p2 + o);
        float4 x3 = *(const float4*)(p3 + o);
        float4 x4 = *(const float4*)(p4 + o);
        float4 res;
        res.x = a.x + 0.5f * (x0.x + x1.x + x2.x + x3.x + x4.x);
        res.y = a.y + 0.5f * (x0.y + x1.y + x2.y + x3.y + x4.y);
        res.z = a.z + 0.5f * (x0.z + x1.z + x2.z + x3.z + x4.z);
        res.w = a.w + 0.5f * (x0.w + x1.w + x2.w + x3.w + x4.w);
        *(float4*)(orow + o) = res;
    }
}

// ---------------- reduce per-row partials -> two scalar outputs ----------------

__global__ __launch_bounds__(1024) void finalize_scal(float* __restrict__ outp) {
    const int t = threadIdx.x;
    float a = 0.f, b = 0.f;
#pragma unroll
    for (int i = 0; i < NB / 1024; i++) {
        a += g_psel[i * 1024 + t];
        b += g_pent[i * 1024 + t];
    }
    for (int off = 32; off; off >>= 1) {
        a += __shfl_xor(a, off);
        b += __shfl_xor(b, off);
    }
    __shared__ float ra[16], rb[16];
    if ((t & 63) == 0) { ra[t >> 6] = a; rb[t >> 6] = b; }
    __syncthreads();
    if (t == 0) {
        float sa = 0.f, sb = 0.f;
#pragma unroll
        for (int i = 0; i < 16; i++) { sa += ra[i]; sb += rb[i]; }
        outp[(size_t)NB * ND] = sa;
        outp[(size_t)NB * ND + 1] = sb;
    }
}

extern "C" void kernel_launch(void* const* d_in, const int* in_sizes, int n_in,
                              void* d_out, int out_size, void* d_ws, size_t ws_size,
                              hipStream_t stream) {
    const float* ppg    = (const float*)d_in[0];
    const float* keys   = (const float*)d_in[1];
    const float* prompt = (const float*)d_in[2];
    float* outp = (float*)d_out;

    const size_t QB_BYTES = (size_t)NB * ND * 2;
    const size_t KB_BYTES = (size_t)NP * ND * 2;
    bool fast = (d_ws != nullptr) && (ws_size >= QB_BYTES + KB_BYTES);
    u16* qb = fast ? (u16*)d_ws : nullptr;
    u16* kb = fast ? (u16*)((char*)d_ws + QB_BYTES) : nullptr;

    prep<<<NB + NP, 256, 0, stream>>>(ppg, keys, qb, kb);
    if (fast) {
        gemm_fast<<<512, 256, 0, stream>>>(qb, kb);
    } else {
        gemm_slow<<<512, 256, 0, stream>>>(ppg, keys);
    }
    post<<<NB, 64, 0, stream>>>(ppg, prompt, outp);
    finalize_scal<<<1, 1024, 0, stream>>>(outp);
}